// Round 17
// baseline (190.929 us; speedup 1.0000x reference)
//
#include <hip/hip_runtime.h>
#include <cfloat>
#include <cstdint>

#define H_    8
#define DH_   128
#define M_    512
#define DIM_  1024
#define BL_   32768

#define BPOS    128          // positions per block
#define THREADS 512          // 8 waves; wave w owns rows [w*16, w*16+16)
#define NC      64           // codes per chunk (double-buffered)
#define NCHUNK  (M_ / NC)    // 8
#define CBUF    16384        // bytes per cb buffer
#define CAP     16
#define EPS     0.02f        // >= 2*maxerr of f16 cross term

typedef _Float16 half8 __attribute__((ext_vector_type(8)));
typedef float floatx4 __attribute__((ext_vector_type(4)));

// workspace layout (bytes): [0, 1MB) swizzled f16 codebook; [1MB, +16KB) f32 csq
#define WS_CB_BYTES (H_ * M_ * DH_ * 2)      // 1048576
#define WS_CSQ_OFF  WS_CB_BYTES

// LDS layout (bytes) -- total 75264 -> 2 blocks/CU
#define OFF_Z16  0                        // 128*256 = 32768 (z tile, f16 swizzled)
#define OFF_CB   (OFF_Z16 + 32768)        // 2 x 16384 = 32768 (cb chunk double buffer)
#define OFF_ZSQ  (OFF_CB + 32768)         // 512  exact f32 |z|^2 (ROUND-1 BIT ORDER)
#define OFF_CSQ  (OFF_ZSQ + 512)          // 2 x 256 = 512 (csq chunk double buffer)
#define OFF_CNT  (OFF_CSQ + 512)          // 512
#define OFF_CI   (OFF_CNT + 512)          // 128*CAP*4 = 8192
#define LDS_TOTAL (OFF_CI + 8192)         // 75264

extern __shared__ char smem[];

__device__ __forceinline__ int swz(int row, int g) { return (g ^ (row & 15)) << 4; }

__device__ __forceinline__ half8 cvt8(float4 a, float4 b) {
    half8 h;
    h[0]=(_Float16)a.x; h[1]=(_Float16)a.y; h[2]=(_Float16)a.z; h[3]=(_Float16)a.w;
    h[4]=(_Float16)b.x; h[5]=(_Float16)b.y; h[6]=(_Float16)b.z; h[7]=(_Float16)b.w;
    return h;
}

// exact fp32 distance with REFERENCE association: d = (zsq + csq) - 2*cross, clamped.
// Bit-order matches rounds 1/3/7-16 (passed). DO NOT ALTER ACCUMULATION ORDER.
__device__ __forceinline__ float exact_d(const float* __restrict__ zr,
                                         const float* __restrict__ cr,
                                         float zsq)
{
    float cx0=0,cx1=0,cx2=0,cx3=0,cq0=0,cq1=0,cq2=0,cq3=0;
    #pragma unroll 8
    for (int k4 = 0; k4 < 32; ++k4) {
        float4 a = *(const float4*)(zr + k4 * 4);
        float4 b = *(const float4*)(cr + k4 * 4);
        cx0 = fmaf(a.x, b.x, cx0); cx1 = fmaf(a.y, b.y, cx1);
        cx2 = fmaf(a.z, b.z, cx2); cx3 = fmaf(a.w, b.w, cx3);
        cq0 = fmaf(b.x, b.x, cq0); cq1 = fmaf(b.y, b.y, cq1);
        cq2 = fmaf(b.z, b.z, cq2); cq3 = fmaf(b.w, b.w, cq3);
    }
    float cross = (cx0 + cx1) + (cx2 + cx3);
    float csqe  = (cq0 + cq1) + (cq2 + cq3);
    float d = (zsq + csqe) - 2.0f * cross;
    return fmaxf(d, 0.f);
}

// ---- prep: codebook f32 -> f16, swizzled into the byte order global_load_lds needs.
__global__ __launch_bounds__(256) void prep_kernel(const float* __restrict__ cbk,
                                                   half8* __restrict__ cbw,
                                                   float* __restrict__ csqw)
{
    int t = blockIdx.x * 256 + threadIdx.x;   // 0..65535 = (h*512+m)*16 + slot
    int g = t & 15;
    int row = t >> 4;                          // h*512 + m  (row&15 == m&15)
    int gs = g ^ (row & 15);
    const float* src = cbk + (size_t)row * DH_ + gs * 8;
    float4 v0 = *(const float4*)src;
    float4 v1 = *(const float4*)(src + 4);
    cbw[row * 16 + g] = cvt8(v0, v1);

    if (g == 0) {   // per-code |c|^2 (filter-only; rounding non-critical)
        const float* cr = cbk + (size_t)row * DH_;
        float ax=0.f, ay=0.f, az=0.f, aw=0.f;
        #pragma unroll
        for (int c4 = 0; c4 < 32; ++c4) {
            float4 v = *(const float4*)(cr + c4 * 4);
            ax = fmaf(v.x, v.x, ax); ay = fmaf(v.y, v.y, ay);
            az = fmaf(v.z, v.z, az); aw = fmaf(v.w, v.w, aw);
        }
        csqw[row] = (ax + ay) + (az + aw);
    }
}

__global__ __launch_bounds__(THREADS, 4) void vq_kernel(
    const float* __restrict__ z,
    const float* __restrict__ cbk,
    const char*  __restrict__ cbw,     // swizzled f16 codebook (ws)
    const float* __restrict__ csqw,    // f32 csq (ws)
    float* __restrict__ out_zq,
    float* __restrict__ out_idx,
    float* __restrict__ out_mind)
{
    char*  z16  = smem + OFF_Z16;
    char*  cbB  = smem + OFF_CB;
    float* zsqS = (float*)(smem + OFF_ZSQ);
    float* csqS = (float*)(smem + OFF_CSQ);
    int*   cntS = (int*)(smem + OFF_CNT);
    int*   candI = (int*)(smem + OFF_CI);

    const int tid   = threadIdx.x;
    const int lane  = tid & 63;
    const int w     = tid >> 6;      // wave -> rows [w*16, w*16+16)
    const int bx    = blockIdx.x;
    const int h     = bx & 7;
    const int posBase = (bx >> 3) * BPOS;

    const float* zBlk = z   + (size_t)posBase * DIM_ + h * DH_;
    const float* cbH  = cbk + (size_t)h * M_ * DH_;
    const char*  cbWH = cbw + (size_t)h * M_ * 256;
    const float* csqHw = csqw + h * M_;

    // ---- issue chunk-0 cb (16KB) + csq (256B) into buffer 0
    #pragma unroll
    for (int it = 0; it < 2; ++it) {
        int off = tid * 16 + it * 8192;
        __builtin_amdgcn_global_load_lds(
            (const __attribute__((address_space(1))) unsigned int*)(cbWH + off),
            (__attribute__((address_space(3))) unsigned int*)(cbB + off),
            16, 0, 0);
    }
    if (tid < 16) {
        int off = tid * 16;
        __builtin_amdgcn_global_load_lds(
            (const __attribute__((address_space(1))) unsigned int*)((const char*)csqHw + off),
            (__attribute__((address_space(3))) unsigned int*)((char*)csqS + off),
            16, 0, 0);
    }

    // ---- PER-WAVE FUSED z stage + exact zsq: lane l<16 of wave w owns row
    //      w*16+l. Identical per-row code & bit order as R14/R16 champion
    //      (c4 = 0..31 ascending via k-pairs, striped-4 fmaf, (ax+ay)+(az+aw));
    //      only the thread->row mapping changed -> ALL 8 waves issue z reads.
    if (lane < 16) {
        const int row = (w << 4) + lane;
        const float* zr = zBlk + (size_t)row * DIM_;
        float ax=0.f, ay=0.f, az=0.f, aw=0.f;
        #pragma unroll
        for (int k = 0; k < 16; ++k) {
            float4 v0 = *(const float4*)(zr + k * 8);
            float4 v1 = *(const float4*)(zr + k * 8 + 4);
            ax = fmaf(v0.x, v0.x, ax); ay = fmaf(v0.y, v0.y, ay);
            az = fmaf(v0.z, v0.z, az); aw = fmaf(v0.w, v0.w, aw);
            ax = fmaf(v1.x, v1.x, ax); ay = fmaf(v1.y, v1.y, ay);
            az = fmaf(v1.z, v1.z, az); aw = fmaf(v1.w, v1.w, aw);
            *(half8*)(z16 + row * 256 + swz(row, k)) = cvt8(v0, v1);
        }
        zsqS[row] = (ax + ay) + (az + aw);
        cntS[row] = 0;
    }
    __syncthreads();   // drains vmcnt: chunk-0 + csq0 resident; z16/zsq/cnt visible

    // ---- A-fragments once (z16 stable; values = RTN f16, same as champion)
    half8 afr[4];
    {
        int row = (w << 4) + (lane & 15);
        #pragma unroll
        for (int ks = 0; ks < 4; ++ks)
            afr[ks] = *(const half8*)(z16 + row * 256 + swz(row, ks * 4 + (lane >> 4)));
    }

    float rmin[4] = {FLT_MAX, FLT_MAX, FLT_MAX, FLT_MAX};

    // ---- T3 pipelined chunk loop: issue ch+1 BEFORE computing ch; ONE barrier
    //      per chunk (its vmcnt(0) drain lands AFTER a full chunk of compute).
    #pragma unroll
    for (int ch = 0; ch < NCHUNK; ++ch) {
        const int mBase = ch * NC;
        const char*  cb   = cbB + (ch & 1) * CBUF;
        const float* csqC = csqS + (ch & 1) * 64;

        // issue NEXT chunk into the other buffer (flies under compute below);
        // WAR-safe: buf (ch+1)&1 was last read in chunk ch-1, barrier'd since.
        if (ch < NCHUNK - 1) {
            const char* src = cbWH + (size_t)(mBase + NC) * 256;
            char* dst = cbB + ((ch + 1) & 1) * CBUF;
            #pragma unroll
            for (int it = 0; it < 2; ++it) {
                int off = tid * 16 + it * 8192;
                __builtin_amdgcn_global_load_lds(
                    (const __attribute__((address_space(1))) unsigned int*)(src + off),
                    (__attribute__((address_space(3))) unsigned int*)(dst + off),
                    16, 0, 0);
            }
            if (tid < 16) {
                int off = tid * 16;
                __builtin_amdgcn_global_load_lds(
                    (const __attribute__((address_space(1))) unsigned int*)((const char*)csqHw + (mBase + NC) * 4 + off),
                    (__attribute__((address_space(3))) unsigned int*)((char*)csqS + ((ch + 1) & 1) * 256 + off),
                    16, 0, 0);
            }
        }

        // ---- MFMA: this wave's 16 rows x the chunk's 64 codes
        floatx4 acc[4];
        #pragma unroll
        for (int nt = 0; nt < 4; ++nt) acc[nt] = (floatx4){0.f, 0.f, 0.f, 0.f};

        #pragma unroll
        for (int ks = 0; ks < 4; ++ks) {
            int g = ks * 4 + (lane >> 4);
            half8 bn[4];
            #pragma unroll
            for (int nt = 0; nt < 4; ++nt) {
                int crow = nt * 16 + (lane & 15);
                bn[nt] = *(const half8*)(cb + crow * 256 + swz(crow, g));
            }
            #pragma unroll
            for (int nt = 0; nt < 4; ++nt)
                acc[nt] = __builtin_amdgcn_mfma_f32_16x16x32_f16(afr[ks], bn[nt], acc[nt], 0, 0, 0);
        }

        // ---- epilogue: v = csq - 2*cross_f16; row-true running min; EPS filter
        float cs[4];
        #pragma unroll
        for (int nt = 0; nt < 4; ++nt) cs[nt] = csqC[nt * 16 + (lane & 15)];
        const int colm = mBase + (lane & 15);

        #pragma unroll
        for (int r = 0; r < 4; ++r) {
            float v[4];
            #pragma unroll
            for (int nt = 0; nt < 4; ++nt) v[nt] = fmaf(-2.f, acc[nt][r], cs[nt]);
            float pm = fminf(fminf(v[0], v[1]), fminf(v[2], v[3]));
            pm = fminf(pm, __shfl_xor(pm, 1, 16));
            pm = fminf(pm, __shfl_xor(pm, 2, 16));
            pm = fminf(pm, __shfl_xor(pm, 4, 16));
            pm = fminf(pm, __shfl_xor(pm, 8, 16));
            rmin[r] = fminf(rmin[r], pm);
            float thr = rmin[r] + EPS;
            int row = (w << 4) + (lane >> 4) * 4 + r;
            #pragma unroll
            for (int nt = 0; nt < 4; ++nt) {
                if (v[nt] <= thr) {
                    int slot = atomicAdd(&cntS[row], 1);
                    if (slot < CAP) candI[row * CAP + slot] = colm + nt * 16;
                }
            }
        }

        __syncthreads();   // ONE barrier/chunk: drains ch+1 loads (hidden under
                           // the compute above) + WAR fence for buffer reuse
    }
    // No barrier: rescue rows are wave-aligned (wave w rescues exactly the rows
    // whose cand lists wave w wrote); same-wave LDS ordering is lgkmcnt-enforced.

    // ---- rescue: UNCONDITIONAL exact fp32 re-rank (round-1/3/7 bit order).
    int bi;
    {
        int row = tid >> 2, j = tid & 3;
        int cnt = cntS[row];
        float zsq = zsqS[row];
        const float* zr = zBlk + (size_t)row * DIM_;

        float bd = FLT_MAX; bi = 0x7fffffff;
        if (cnt > CAP) {
            // overflow (rare): racy drop set -> ignore list, deterministic full scan
            for (int m = j; m < M_; m += 4) {
                float d = exact_d(zr, cbH + (size_t)m * DH_, zsq);
                if (d < bd || (d == bd && m < bi)) { bd = d; bi = m; }
            }
        } else {
            for (int c = j; c < cnt; c += 4) {
                int m = candI[row * CAP + c];
                float d = exact_d(zr, cbH + (size_t)m * DH_, zsq);
                if (d < bd || (d == bd && m < bi)) { bd = d; bi = m; }
            }
        }
        #pragma unroll
        for (int off = 1; off < 4; off <<= 1) {
            float od = __shfl_xor(bd, off, 4);
            int   oi = __shfl_xor(bi, off, 4);
            if (od < bd || (od == bd && oi < bi)) { bd = od; bi = oi; }
        }
        if (bi < 0 || bi >= M_) bi = 0;       // unreachable guard: never fault the gather
        if (j == 0) {
            size_t gp = (size_t)(posBase + row) * H_ + h;
            out_idx[gp]  = (float)bi;
            out_mind[gp] = bd;
        }
    }

    // ---- z_q gather + store: wave-local (winner via shfl).
    #pragma unroll
    for (int it = 0; it < 8; ++it) {
        int rl2 = it * 2 + (lane >> 5);           // 0..15 : row within wave
        int c4  = lane & 31;
        int m = __shfl(bi, rl2 << 2, 64);         // winner of row 16w + rl2
        float4 v = *(const float4*)(cbH + (size_t)m * DH_ + c4 * 4);
        *(float4*)(out_zq + (size_t)(posBase + (w << 4) + rl2) * DIM_ + h * DH_ + c4 * 4) = v;
    }
}

extern "C" void kernel_launch(void* const* d_in, const int* in_sizes, int n_in,
                              void* d_out, int out_size, void* d_ws, size_t ws_size,
                              hipStream_t stream) {
    const float* z   = (const float*)d_in[0];
    const float* cbk = (const float*)d_in[1];

    float* zq    = (float*)d_out;
    float* oidx  = zq + (size_t)BL_ * DIM_;
    float* omind = oidx + (size_t)BL_ * H_;

    half8* cbw  = (half8*)d_ws;
    float* csqw = (float*)((char*)d_ws + WS_CSQ_OFF);

    hipLaunchKernelGGL(prep_kernel, dim3(256), dim3(256), 0, stream,
                       cbk, cbw, csqw);

    hipFuncSetAttribute((const void*)vq_kernel,
                        hipFuncAttributeMaxDynamicSharedMemorySize, LDS_TOTAL);

    dim3 grid((BL_ / BPOS) * H_);   // 256 * 8 = 2048
    dim3 block(THREADS);
    hipLaunchKernelGGL(vq_kernel, grid, block, LDS_TOTAL, stream,
                       z, cbk, (const char*)cbw, csqw, zq, oidx, omind);
}

// Round 18
// 161.062 us; speedup vs baseline: 1.1854x; 1.1854x over previous
//
#include <hip/hip_runtime.h>
#include <cfloat>
#include <cstdint>

#define H_    8
#define DH_   128
#define M_    512
#define DIM_  1024
#define BL_   32768

#define BPOS    128          // positions per block
#define THREADS 512          // 8 waves; wave w owns rows [w*16, w*16+16)
#define NC      128          // codes per chunk
#define NCHUNK  (M_ / NC)    // 4
#define CAP     16
#define EPS     0.02f        // >= 2*maxerr of f16 cross term

typedef _Float16 half8 __attribute__((ext_vector_type(8)));
typedef float floatx4 __attribute__((ext_vector_type(4)));

// workspace layout (bytes): [0, 1MB) swizzled f16 codebook; [1MB, +16KB) f32 csq
#define WS_CB_BYTES (H_ * M_ * DH_ * 2)      // 1048576
#define WS_CSQ_OFF  WS_CB_BYTES

// LDS layout (bytes) -- total 75264 -> 2 blocks/CU
#define OFF_Z16  0                        // 128*256 = 32768 (z tile, f16 swizzled)
#define OFF_CB   (OFF_Z16 + 32768)        // 128*256 = 32768 (cb chunk, f16 pre-swizzled)
#define OFF_ZSQ  (OFF_CB + 32768)         // 512  exact f32 |z|^2 (ROUND-1 BIT ORDER)
#define OFF_CSQ  (OFF_ZSQ + 512)          // 512  f32 |c|^2 chunk (filter only)
#define OFF_CNT  (OFF_CSQ + 512)          // 512
#define OFF_CI   (OFF_CNT + 512)          // 128*CAP*4 = 8192
#define LDS_TOTAL (OFF_CI + 8192)         // 75264

extern __shared__ char smem[];

__device__ __forceinline__ int swz(int row, int g) { return (g ^ (row & 15)) << 4; }

__device__ __forceinline__ half8 cvt8(float4 a, float4 b) {
    half8 h;
    h[0]=(_Float16)a.x; h[1]=(_Float16)a.y; h[2]=(_Float16)a.z; h[3]=(_Float16)a.w;
    h[4]=(_Float16)b.x; h[5]=(_Float16)b.y; h[6]=(_Float16)b.z; h[7]=(_Float16)b.w;
    return h;
}

// exact fp32 distance with REFERENCE association: d = (zsq + csq) - 2*cross, clamped.
// Bit-order matches rounds 1/3/7-17 (passed). DO NOT ALTER ACCUMULATION ORDER.
__device__ __forceinline__ float exact_d(const float* __restrict__ zr,
                                         const float* __restrict__ cr,
                                         float zsq)
{
    float cx0=0,cx1=0,cx2=0,cx3=0,cq0=0,cq1=0,cq2=0,cq3=0;
    #pragma unroll 8
    for (int k4 = 0; k4 < 32; ++k4) {
        float4 a = *(const float4*)(zr + k4 * 4);
        float4 b = *(const float4*)(cr + k4 * 4);
        cx0 = fmaf(a.x, b.x, cx0); cx1 = fmaf(a.y, b.y, cx1);
        cx2 = fmaf(a.z, b.z, cx2); cx3 = fmaf(a.w, b.w, cx3);
        cq0 = fmaf(b.x, b.x, cq0); cq1 = fmaf(b.y, b.y, cq1);
        cq2 = fmaf(b.z, b.z, cq2); cq3 = fmaf(b.w, b.w, cq3);
    }
    float cross = (cx0 + cx1) + (cx2 + cx3);
    float csqe  = (cq0 + cq1) + (cq2 + cq3);
    float d = (zsq + csqe) - 2.0f * cross;
    return fmaxf(d, 0.f);
}

// ---- prep: codebook f32 -> f16, swizzled into the byte order global_load_lds needs.
__global__ __launch_bounds__(256) void prep_kernel(const float* __restrict__ cbk,
                                                   half8* __restrict__ cbw,
                                                   float* __restrict__ csqw)
{
    int t = blockIdx.x * 256 + threadIdx.x;   // 0..65535 = (h*512+m)*16 + slot
    int g = t & 15;
    int row = t >> 4;                          // h*512 + m  (row&15 == m&15)
    int gs = g ^ (row & 15);
    const float* src = cbk + (size_t)row * DH_ + gs * 8;
    float4 v0 = *(const float4*)src;
    float4 v1 = *(const float4*)(src + 4);
    cbw[row * 16 + g] = cvt8(v0, v1);

    if (g == 0) {   // per-code |c|^2 (filter-only; rounding non-critical)
        const float* cr = cbk + (size_t)row * DH_;
        float ax=0.f, ay=0.f, az=0.f, aw=0.f;
        #pragma unroll
        for (int c4 = 0; c4 < 32; ++c4) {
            float4 v = *(const float4*)(cr + c4 * 4);
            ax = fmaf(v.x, v.x, ax); ay = fmaf(v.y, v.y, ay);
            az = fmaf(v.z, v.z, az); aw = fmaf(v.w, v.w, aw);
        }
        csqw[row] = (ax + ay) + (az + aw);
    }
}

__global__ __launch_bounds__(THREADS, 4) void vq_kernel(
    const float* __restrict__ z,
    const float* __restrict__ cbk,
    const char*  __restrict__ cbw,     // swizzled f16 codebook (ws)
    const float* __restrict__ csqw,    // f32 csq (ws)
    float* __restrict__ out_zq,
    float* __restrict__ out_idx,
    float* __restrict__ out_mind)
{
    char*  z16  = smem + OFF_Z16;
    char*  cbB  = smem + OFF_CB;
    float* zsqS = (float*)(smem + OFF_ZSQ);
    float* csqS = (float*)(smem + OFF_CSQ);
    int*   cntS = (int*)(smem + OFF_CNT);
    int*   candI = (int*)(smem + OFF_CI);

    const int tid   = threadIdx.x;
    const int lane  = tid & 63;
    const int w     = tid >> 6;      // wave -> rows [w*16, w*16+16)
    const int bx    = blockIdx.x;
    const int h     = bx & 7;
    const int posBase = (bx >> 3) * BPOS;

    const float* zBlk = z   + (size_t)posBase * DIM_ + h * DH_;
    const float* cbH  = cbk + (size_t)h * M_ * DH_;
    const char*  cbWH = cbw + (size_t)h * M_ * 256;
    const float* csqHw = csqw + h * M_;

    // ---- issue chunk-0 cb (32KB) + csq (512B) via global_load_lds (no VGPR trip)
    #pragma unroll
    for (int it = 0; it < 4; ++it) {
        int off = tid * 16 + it * 8192;
        __builtin_amdgcn_global_load_lds(
            (const __attribute__((address_space(1))) unsigned int*)(cbWH + off),
            (__attribute__((address_space(3))) unsigned int*)(cbB + off),
            16, 0, 0);
    }
    if (tid < 32) {
        int off = tid * 16;
        __builtin_amdgcn_global_load_lds(
            (const __attribute__((address_space(1))) unsigned int*)((const char*)csqHw + off),
            (__attribute__((address_space(3))) unsigned int*)((char*)csqS + off),
            16, 0, 0);
    }

    // ---- PER-WAVE FUSED z stage + exact zsq: lane l<16 of wave w owns row
    //      w*16+l. Per-row code & bit order CHARACTER-IDENTICAL to champion
    //      (c4 = 0..31 ascending via k-pairs, striped-4 fmaf, (ax+ay)+(az+aw));
    //      only the thread->row mapping changed -> ALL 8 waves issue z reads,
    //      and each wave ds_writes its own 4KB z16 slice (2-way banks = free).
    if (lane < 16) {
        const int row = (w << 4) + lane;
        const float* zr = zBlk + (size_t)row * DIM_;
        float ax=0.f, ay=0.f, az=0.f, aw=0.f;
        #pragma unroll
        for (int k = 0; k < 16; ++k) {
            float4 v0 = *(const float4*)(zr + k * 8);
            float4 v1 = *(const float4*)(zr + k * 8 + 4);
            ax = fmaf(v0.x, v0.x, ax); ay = fmaf(v0.y, v0.y, ay);
            az = fmaf(v0.z, v0.z, az); aw = fmaf(v0.w, v0.w, aw);
            ax = fmaf(v1.x, v1.x, ax); ay = fmaf(v1.y, v1.y, ay);
            az = fmaf(v1.z, v1.z, az); aw = fmaf(v1.w, v1.w, aw);
            *(half8*)(z16 + row * 256 + swz(row, k)) = cvt8(v0, v1);
        }
        zsqS[row] = (ax + ay) + (az + aw);
        cntS[row] = 0;
    }
    __syncthreads();   // drains vmcnt: chunk-0 + csq resident; z16/zsq/cnt visible

    // ---- A-fragments once (z16 stable; values = RTN f16, same as champion)
    half8 afr[4];
    {
        int row = (w << 4) + (lane & 15);
        #pragma unroll
        for (int ks = 0; ks < 4; ++ks)
            afr[ks] = *(const half8*)(z16 + row * 256 + swz(row, ks * 4 + (lane >> 4)));
    }

    float rmin[4] = {FLT_MAX, FLT_MAX, FLT_MAX, FLT_MAX};

    #pragma unroll
    for (int ch = 0; ch < NCHUNK; ++ch) {
        const int mBase = ch * NC;

        // ---- MFMA: this wave's 16 rows x all 128 codes of the chunk
        floatx4 acc[8];
        #pragma unroll
        for (int nt = 0; nt < 8; ++nt) acc[nt] = (floatx4){0.f, 0.f, 0.f, 0.f};

        #pragma unroll
        for (int ks = 0; ks < 4; ++ks) {
            int g = ks * 4 + (lane >> 4);
            half8 bn[8];
            #pragma unroll
            for (int nt = 0; nt < 8; ++nt) {
                int crow = nt * 16 + (lane & 15);
                bn[nt] = *(const half8*)(cbB + crow * 256 + swz(crow, g));
            }
            #pragma unroll
            for (int nt = 0; nt < 8; ++nt)
                acc[nt] = __builtin_amdgcn_mfma_f32_16x16x32_f16(afr[ks], bn[nt], acc[nt], 0, 0, 0);
        }

        // ---- epilogue: v = csq - 2*cross_f16; row-true running min; EPS filter
        float cs[8];
        #pragma unroll
        for (int nt = 0; nt < 8; ++nt) cs[nt] = csqS[nt * 16 + (lane & 15)];
        const int colm = mBase + (lane & 15);

        #pragma unroll
        for (int r = 0; r < 4; ++r) {
            float v[8];
            #pragma unroll
            for (int nt = 0; nt < 8; ++nt) v[nt] = fmaf(-2.f, acc[nt][r], cs[nt]);
            float pm = fminf(fminf(fminf(v[0], v[1]), fminf(v[2], v[3])),
                             fminf(fminf(v[4], v[5]), fminf(v[6], v[7])));
            pm = fminf(pm, __shfl_xor(pm, 1, 16));
            pm = fminf(pm, __shfl_xor(pm, 2, 16));
            pm = fminf(pm, __shfl_xor(pm, 4, 16));
            pm = fminf(pm, __shfl_xor(pm, 8, 16));
            rmin[r] = fminf(rmin[r], pm);
            float thr = rmin[r] + EPS;
            int row = (w << 4) + (lane >> 4) * 4 + r;
            #pragma unroll
            for (int nt = 0; nt < 8; ++nt) {
                if (v[nt] <= thr) {
                    int slot = atomicAdd(&cntS[row], 1);
                    if (slot < CAP) candI[row * CAP + slot] = colm + nt * 16;
                }
            }
        }

        // ---- rotate buffer: all waves done reading -> stage next chunk
        if (ch < NCHUNK - 1) {
            __syncthreads();   // done reading cbB/csqS
            const char* src = cbWH + (size_t)(mBase + NC) * 256;
            #pragma unroll
            for (int it = 0; it < 4; ++it) {
                int off = tid * 16 + it * 8192;
                __builtin_amdgcn_global_load_lds(
                    (const __attribute__((address_space(1))) unsigned int*)(src + off),
                    (__attribute__((address_space(3))) unsigned int*)(cbB + off),
                    16, 0, 0);
            }
            if (tid < 32) {
                int off = tid * 16;
                __builtin_amdgcn_global_load_lds(
                    (const __attribute__((address_space(1))) unsigned int*)((const char*)csqHw + (mBase + NC) * 4 + off),
                    (__attribute__((address_space(3))) unsigned int*)((char*)csqS + off),
                    16, 0, 0);
            }
            __syncthreads();   // drains vmcnt: next chunk resident
        }
    }
    // No barrier: rescue rows are wave-aligned (wave w rescues exactly the rows
    // whose cand lists wave w wrote); same-wave LDS ordering is lgkmcnt-enforced.

    // ---- rescue: UNCONDITIONAL exact fp32 re-rank (round-1/3/7 bit order).
    int bi;
    {
        int row = tid >> 2, j = tid & 3;
        int cnt = cntS[row];
        float zsq = zsqS[row];
        const float* zr = zBlk + (size_t)row * DIM_;

        float bd = FLT_MAX; bi = 0x7fffffff;
        if (cnt > CAP) {
            // overflow (rare): racy drop set -> ignore list, deterministic full scan
            for (int m = j; m < M_; m += 4) {
                float d = exact_d(zr, cbH + (size_t)m * DH_, zsq);
                if (d < bd || (d == bd && m < bi)) { bd = d; bi = m; }
            }
        } else {
            for (int c = j; c < cnt; c += 4) {
                int m = candI[row * CAP + c];
                float d = exact_d(zr, cbH + (size_t)m * DH_, zsq);
                if (d < bd || (d == bd && m < bi)) { bd = d; bi = m; }
            }
        }
        #pragma unroll
        for (int off = 1; off < 4; off <<= 1) {
            float od = __shfl_xor(bd, off, 4);
            int   oi = __shfl_xor(bi, off, 4);
            if (od < bd || (od == bd && oi < bi)) { bd = od; bi = oi; }
        }
        if (bi < 0 || bi >= M_) bi = 0;       // unreachable guard: never fault the gather
        if (j == 0) {
            size_t gp = (size_t)(posBase + row) * H_ + h;
            out_idx[gp]  = (float)bi;
            out_mind[gp] = bd;
        }
    }

    // ---- z_q gather + store: wave-local (winner via shfl).
    #pragma unroll
    for (int it = 0; it < 8; ++it) {
        int rl2 = it * 2 + (lane >> 5);           // 0..15 : row within wave
        int c4  = lane & 31;
        int m = __shfl(bi, rl2 << 2, 64);         // winner of row 16w + rl2
        float4 v = *(const float4*)(cbH + (size_t)m * DH_ + c4 * 4);
        *(float4*)(out_zq + (size_t)(posBase + (w << 4) + rl2) * DIM_ + h * DH_ + c4 * 4) = v;
    }
}

extern "C" void kernel_launch(void* const* d_in, const int* in_sizes, int n_in,
                              void* d_out, int out_size, void* d_ws, size_t ws_size,
                              hipStream_t stream) {
    const float* z   = (const float*)d_in[0];
    const float* cbk = (const float*)d_in[1];

    float* zq    = (float*)d_out;
    float* oidx  = zq + (size_t)BL_ * DIM_;
    float* omind = oidx + (size_t)BL_ * H_;

    half8* cbw  = (half8*)d_ws;
    float* csqw = (float*)((char*)d_ws + WS_CSQ_OFF);

    hipLaunchKernelGGL(prep_kernel, dim3(256), dim3(256), 0, stream,
                       cbk, cbw, csqw);

    hipFuncSetAttribute((const void*)vq_kernel,
                        hipFuncAttributeMaxDynamicSharedMemorySize, LDS_TOTAL);

    dim3 grid((BL_ / BPOS) * H_);   // 256 * 8 = 2048
    dim3 block(THREADS);
    hipLaunchKernelGGL(vq_kernel, grid, block, LDS_TOTAL, stream,
                       z, cbk, (const char*)cbw, csqw, zq, oidx, omind);
}

// Round 19
// 153.747 us; speedup vs baseline: 1.2418x; 1.0476x over previous
//
#include <hip/hip_runtime.h>
#include <cfloat>
#include <cstdint>

#define H_    8
#define DH_   128
#define M_    512
#define DIM_  1024
#define BL_   32768

#define BPOS    128          // positions per block
#define THREADS 512          // 8 waves; wave w owns rows [w*16, w*16+16)
#define NC      128          // codes per chunk
#define NCHUNK  (M_ / NC)    // 4
#define CAP     16
#define EPS     0.02f        // >= 2*maxerr of f16 cross term

typedef _Float16 half8 __attribute__((ext_vector_type(8)));
typedef float floatx4 __attribute__((ext_vector_type(4)));

// workspace layout (bytes): [0, 1MB) swizzled f16 codebook; [1MB, +16KB) f32 csq
#define WS_CB_BYTES (H_ * M_ * DH_ * 2)      // 1048576
#define WS_CSQ_OFF  WS_CB_BYTES

// LDS layout (bytes) -- total 75264 -> 2 blocks/CU
#define OFF_Z16  0                        // 128*256 = 32768 (z tile, f16 swizzled)
#define OFF_CB   (OFF_Z16 + 32768)        // 128*256 = 32768 (cb chunk, f16 pre-swizzled)
#define OFF_ZSQ  (OFF_CB + 32768)         // 512  exact f32 |z|^2 (ROUND-1 BIT ORDER)
#define OFF_CSQ  (OFF_ZSQ + 512)          // 512  f32 |c|^2 chunk (filter only)
#define OFF_CNT  (OFF_CSQ + 512)          // 512
#define OFF_CI   (OFF_CNT + 512)          // 128*CAP*4 = 8192
#define LDS_TOTAL (OFF_CI + 8192)         // 75264

extern __shared__ char smem[];

__device__ __forceinline__ int swz(int row, int g) { return (g ^ (row & 15)) << 4; }

__device__ __forceinline__ half8 cvt8(float4 a, float4 b) {
    half8 h;
    h[0]=(_Float16)a.x; h[1]=(_Float16)a.y; h[2]=(_Float16)a.z; h[3]=(_Float16)a.w;
    h[4]=(_Float16)b.x; h[5]=(_Float16)b.y; h[6]=(_Float16)b.z; h[7]=(_Float16)b.w;
    return h;
}

// exact fp32 distance with REFERENCE association: d = (zsq + csq) - 2*cross, clamped.
// Bit-order matches rounds 1/3/7-18 (passed). DO NOT ALTER ACCUMULATION ORDER.
__device__ __forceinline__ float exact_d(const float* __restrict__ zr,
                                         const float* __restrict__ cr,
                                         float zsq)
{
    float cx0=0,cx1=0,cx2=0,cx3=0,cq0=0,cq1=0,cq2=0,cq3=0;
    #pragma unroll 8
    for (int k4 = 0; k4 < 32; ++k4) {
        float4 a = *(const float4*)(zr + k4 * 4);
        float4 b = *(const float4*)(cr + k4 * 4);
        cx0 = fmaf(a.x, b.x, cx0); cx1 = fmaf(a.y, b.y, cx1);
        cx2 = fmaf(a.z, b.z, cx2); cx3 = fmaf(a.w, b.w, cx3);
        cq0 = fmaf(b.x, b.x, cq0); cq1 = fmaf(b.y, b.y, cq1);
        cq2 = fmaf(b.z, b.z, cq2); cq3 = fmaf(b.w, b.w, cq3);
    }
    float cross = (cx0 + cx1) + (cx2 + cx3);
    float csqe  = (cq0 + cq1) + (cq2 + cq3);
    float d = (zsq + csqe) - 2.0f * cross;
    return fmaxf(d, 0.f);
}

// ---- prep: codebook f32 -> f16, swizzled into the byte order global_load_lds needs.
__global__ __launch_bounds__(256) void prep_kernel(const float* __restrict__ cbk,
                                                   half8* __restrict__ cbw,
                                                   float* __restrict__ csqw)
{
    int t = blockIdx.x * 256 + threadIdx.x;   // 0..65535 = (h*512+m)*16 + slot
    int g = t & 15;
    int row = t >> 4;                          // h*512 + m  (row&15 == m&15)
    int gs = g ^ (row & 15);
    const float* src = cbk + (size_t)row * DH_ + gs * 8;
    float4 v0 = *(const float4*)src;
    float4 v1 = *(const float4*)(src + 4);
    cbw[row * 16 + g] = cvt8(v0, v1);

    if (g == 0) {   // per-code |c|^2 (filter-only; rounding non-critical)
        const float* cr = cbk + (size_t)row * DH_;
        float ax=0.f, ay=0.f, az=0.f, aw=0.f;
        #pragma unroll
        for (int c4 = 0; c4 < 32; ++c4) {
            float4 v = *(const float4*)(cr + c4 * 4);
            ax = fmaf(v.x, v.x, ax); ay = fmaf(v.y, v.y, ay);
            az = fmaf(v.z, v.z, az); aw = fmaf(v.w, v.w, aw);
        }
        csqw[row] = (ax + ay) + (az + aw);
    }
}

__global__ __launch_bounds__(THREADS, 4) void vq_kernel(
    const float* __restrict__ z,
    const float* __restrict__ cbk,
    const char*  __restrict__ cbw,     // swizzled f16 codebook (ws)
    const float* __restrict__ csqw,    // f32 csq (ws)
    float* __restrict__ out_zq,
    float* __restrict__ out_idx,
    float* __restrict__ out_mind)
{
    char*  z16  = smem + OFF_Z16;
    char*  cbB  = smem + OFF_CB;
    float* zsqS = (float*)(smem + OFF_ZSQ);
    float* csqS = (float*)(smem + OFF_CSQ);
    int*   cntS = (int*)(smem + OFF_CNT);
    int*   candI = (int*)(smem + OFF_CI);

    const int tid   = threadIdx.x;
    const int lane  = tid & 63;
    const int w     = tid >> 6;      // wave -> rows [w*16, w*16+16)
    const int bx    = blockIdx.x;
    const int h     = bx & 7;
    const int posBase = (bx >> 3) * BPOS;

    const float* zBlk = z   + (size_t)posBase * DIM_ + h * DH_;
    const float* cbH  = cbk + (size_t)h * M_ * DH_;
    const char*  cbWH = cbw + (size_t)h * M_ * 256;
    const float* csqHw = csqw + h * M_;

    // ---- issue chunk-0 cb (32KB) + csq (512B) via global_load_lds (no VGPR trip)
    #pragma unroll
    for (int it = 0; it < 4; ++it) {
        int off = tid * 16 + it * 8192;
        __builtin_amdgcn_global_load_lds(
            (const __attribute__((address_space(1))) unsigned int*)(cbWH + off),
            (__attribute__((address_space(3))) unsigned int*)(cbB + off),
            16, 0, 0);
    }
    if (tid < 32) {
        int off = tid * 16;
        __builtin_amdgcn_global_load_lds(
            (const __attribute__((address_space(1))) unsigned int*)((const char*)csqHw + off),
            (__attribute__((address_space(3))) unsigned int*)((char*)csqS + off),
            16, 0, 0);
    }
    if (tid < BPOS) cntS[tid] = 0;

    // ---- FUSED z stage + exact zsq (champion form): one thread per row;
    //      the SAME sequential float4 reads feed both the f16 LDS tile and the
    //      R1-bit-order zsq (c4 = 0..31 ascending, striped-4, (ax+ay)+(az+aw)).
    if (tid < BPOS) {
        const float* zr = zBlk + (size_t)tid * DIM_;
        float ax=0.f, ay=0.f, az=0.f, aw=0.f;
        #pragma unroll
        for (int k = 0; k < 16; ++k) {
            float4 v0 = *(const float4*)(zr + k * 8);
            float4 v1 = *(const float4*)(zr + k * 8 + 4);
            ax = fmaf(v0.x, v0.x, ax); ay = fmaf(v0.y, v0.y, ay);
            az = fmaf(v0.z, v0.z, az); aw = fmaf(v0.w, v0.w, aw);
            ax = fmaf(v1.x, v1.x, ax); ay = fmaf(v1.y, v1.y, ay);
            az = fmaf(v1.z, v1.z, az); aw = fmaf(v1.w, v1.w, aw);
            *(half8*)(z16 + tid * 256 + swz(tid, k)) = cvt8(v0, v1);
        }
        zsqS[tid] = (ax + ay) + (az + aw);
    }
    __syncthreads();   // drains vmcnt: chunk-0 + csq resident; z16/zsq/cnt visible

    // ---- A-fragments once (z16 stable; values = RTN f16, same as champion)
    half8 afr[4];
    {
        int row = (w << 4) + (lane & 15);
        #pragma unroll
        for (int ks = 0; ks < 4; ++ks)
            afr[ks] = *(const half8*)(z16 + row * 256 + swz(row, ks * 4 + (lane >> 4)));
    }

    float rmin[4] = {FLT_MAX, FLT_MAX, FLT_MAX, FLT_MAX};

    #pragma unroll
    for (int ch = 0; ch < NCHUNK; ++ch) {
        const int mBase = ch * NC;

        // ---- MFMA: this wave's 16 rows x all 128 codes of the chunk
        floatx4 acc[8];
        #pragma unroll
        for (int nt = 0; nt < 8; ++nt) acc[nt] = (floatx4){0.f, 0.f, 0.f, 0.f};

        #pragma unroll
        for (int ks = 0; ks < 4; ++ks) {
            int g = ks * 4 + (lane >> 4);
            half8 bn[8];
            #pragma unroll
            for (int nt = 0; nt < 8; ++nt) {
                int crow = nt * 16 + (lane & 15);
                bn[nt] = *(const half8*)(cbB + crow * 256 + swz(crow, g));
            }
            #pragma unroll
            for (int nt = 0; nt < 8; ++nt)
                acc[nt] = __builtin_amdgcn_mfma_f32_16x16x32_f16(afr[ks], bn[nt], acc[nt], 0, 0, 0);
        }

        // ---- epilogue: v = csq - 2*cross_f16; row-true running min; EPS filter
        float cs[8];
        #pragma unroll
        for (int nt = 0; nt < 8; ++nt) cs[nt] = csqS[nt * 16 + (lane & 15)];
        const int colm = mBase + (lane & 15);

        #pragma unroll
        for (int r = 0; r < 4; ++r) {
            float v[8];
            #pragma unroll
            for (int nt = 0; nt < 8; ++nt) v[nt] = fmaf(-2.f, acc[nt][r], cs[nt]);
            float pm = fminf(fminf(fminf(v[0], v[1]), fminf(v[2], v[3])),
                             fminf(fminf(v[4], v[5]), fminf(v[6], v[7])));
            pm = fminf(pm, __shfl_xor(pm, 1, 16));
            pm = fminf(pm, __shfl_xor(pm, 2, 16));
            pm = fminf(pm, __shfl_xor(pm, 4, 16));
            pm = fminf(pm, __shfl_xor(pm, 8, 16));
            rmin[r] = fminf(rmin[r], pm);
            float thr = rmin[r] + EPS;
            int row = (w << 4) + (lane >> 4) * 4 + r;
            #pragma unroll
            for (int nt = 0; nt < 8; ++nt) {
                if (v[nt] <= thr) {
                    int slot = atomicAdd(&cntS[row], 1);
                    if (slot < CAP) candI[row * CAP + slot] = colm + nt * 16;
                }
            }
        }

        // ---- rotate buffer: all waves done reading -> stage next chunk
        if (ch < NCHUNK - 1) {
            __syncthreads();   // done reading cbB/csqS
            const char* src = cbWH + (size_t)(mBase + NC) * 256;
            #pragma unroll
            for (int it = 0; it < 4; ++it) {
                int off = tid * 16 + it * 8192;
                __builtin_amdgcn_global_load_lds(
                    (const __attribute__((address_space(1))) unsigned int*)(src + off),
                    (__attribute__((address_space(3))) unsigned int*)(cbB + off),
                    16, 0, 0);
            }
            if (tid < 32) {
                int off = tid * 16;
                __builtin_amdgcn_global_load_lds(
                    (const __attribute__((address_space(1))) unsigned int*)((const char*)csqHw + (mBase + NC) * 4 + off),
                    (__attribute__((address_space(3))) unsigned int*)((char*)csqS + off),
                    16, 0, 0);
            }
            __syncthreads();   // drains vmcnt: next chunk resident
        }
    }
    // No barrier: rescue rows are wave-aligned (wave w rescues exactly the rows
    // whose cand lists wave w wrote); same-wave LDS ordering is lgkmcnt-enforced.

    // ---- rescue: UNCONDITIONAL exact fp32 re-rank (round-1/3/7 bit order).
    int bi;
    {
        int row = tid >> 2, j = tid & 3;
        int cnt = cntS[row];
        float zsq = zsqS[row];
        const float* zr = zBlk + (size_t)row * DIM_;

        float bd = FLT_MAX; bi = 0x7fffffff;
        if (cnt > CAP) {
            // overflow (rare): racy drop set -> ignore list, deterministic full scan
            for (int m = j; m < M_; m += 4) {
                float d = exact_d(zr, cbH + (size_t)m * DH_, zsq);
                if (d < bd || (d == bd && m < bi)) { bd = d; bi = m; }
            }
        } else {
            for (int c = j; c < cnt; c += 4) {
                int m = candI[row * CAP + c];
                float d = exact_d(zr, cbH + (size_t)m * DH_, zsq);
                if (d < bd || (d == bd && m < bi)) { bd = d; bi = m; }
            }
        }
        #pragma unroll
        for (int off = 1; off < 4; off <<= 1) {
            float od = __shfl_xor(bd, off, 4);
            int   oi = __shfl_xor(bi, off, 4);
            if (od < bd || (od == bd && oi < bi)) { bd = od; bi = oi; }
        }
        if (bi < 0 || bi >= M_) bi = 0;       // unreachable guard: never fault the gather
        if (j == 0) {
            size_t gp = (size_t)(posBase + row) * H_ + h;
            out_idx[gp]  = (float)bi;
            out_mind[gp] = bd;
        }
    }

    // ---- z_q gather + store: wave-local (winner via shfl).
    #pragma unroll
    for (int it = 0; it < 8; ++it) {
        int rl2 = it * 2 + (lane >> 5);           // 0..15 : row within wave
        int c4  = lane & 31;
        int m = __shfl(bi, rl2 << 2, 64);         // winner of row 16w + rl2
        float4 v = *(const float4*)(cbH + (size_t)m * DH_ + c4 * 4);
        *(float4*)(out_zq + (size_t)(posBase + (w << 4) + rl2) * DIM_ + h * DH_ + c4 * 4) = v;
    }
}

extern "C" void kernel_launch(void* const* d_in, const int* in_sizes, int n_in,
                              void* d_out, int out_size, void* d_ws, size_t ws_size,
                              hipStream_t stream) {
    const float* z   = (const float*)d_in[0];
    const float* cbk = (const float*)d_in[1];

    float* zq    = (float*)d_out;
    float* oidx  = zq + (size_t)BL_ * DIM_;
    float* omind = oidx + (size_t)BL_ * H_;

    half8* cbw  = (half8*)d_ws;
    float* csqw = (float*)((char*)d_ws + WS_CSQ_OFF);

    hipLaunchKernelGGL(prep_kernel, dim3(256), dim3(256), 0, stream,
                       cbk, cbw, csqw);

    hipFuncSetAttribute((const void*)vq_kernel,
                        hipFuncAttributeMaxDynamicSharedMemorySize, LDS_TOTAL);

    dim3 grid((BL_ / BPOS) * H_);   // 256 * 8 = 2048
    dim3 block(THREADS);
    hipLaunchKernelGGL(vq_kernel, grid, block, LDS_TOTAL, stream,
                       z, cbk, (const char*)cbw, csqw, zq, oidx, omind);
}